// Round 4
// baseline (82.707 us; speedup 1.0000x reference)
//
#include <hip/hip_runtime.h>
#include <math.h>

#define D    32
#define PREV 64
#define HID  128
#define HDIM 64
#define BPB  32      // batches per main block
#define TPB  512     // 8 waves

// ws float layout (all regions fully rewritten by prep every call):
//   [0,4096)      M[h*32+d]   = sum_p w1[d,p]*bw[h,p]
//   [4096,4224)   sbias[h]    = b1.bw[h,:] + bb[h]
//   [8192,12288)  w2T[h*32+d] = w2[d,h]

// ---------------- DPP reduction helpers (verified R1/R3) ----------------
#define DPP_QUAD_XOR1   0xB1   // quad_perm(1,0,3,2)
#define DPP_QUAD_XOR2   0x4E   // quad_perm(2,3,0,1)
#define DPP_ROW_ROR4    0x124
#define DPP_ROW_ROR8    0x128
#define DPP_ROW_BCAST15 0x142

template <int CTRL>
__device__ __forceinline__ float dpp_radd(float v) {
    int t = __builtin_amdgcn_update_dpp(0, __float_as_int(v), CTRL, 0xF, 0xF, true);
    return v + __int_as_float(t);
}

__device__ __forceinline__ float reduce32(float v) {
    v = dpp_radd<DPP_QUAD_XOR1>(v);
    v = dpp_radd<DPP_QUAD_XOR2>(v);
    v = dpp_radd<DPP_ROW_ROR4>(v);
    v = dpp_radd<DPP_ROW_ROR8>(v);
    v = dpp_radd<DPP_ROW_BCAST15>(v);
    return v;
}

// grid 33 x 128 (was 17): block b in [0,32) owns ONE d-column. Halves
// per-block work vs the 17-block version and doubles block-level parallelism;
// longest dependent dot chain halved (half-row per thread + 1 shfl).
// Block 32: b1 + sbias (unchanged structure).
__global__ __launch_bounds__(128) void prep_kernel(
    const float* __restrict__ t,
    const float* __restrict__ hw1,
    const float* __restrict__ hb1,
    const float* __restrict__ hw2,
    const float* __restrict__ hb2,
    const float* __restrict__ bw,
    const float* __restrict__ bb,
    const float* __restrict__ w2,
    float* __restrict__ ws)
{
    __shared__ float hcode[HDIM];
    __shared__ float w1d[PREV];    // this block's w1 row (weights d*64 .. d*64+63)
    __shared__ float b1s[PREV];

    const int tid = threadIdx.x;
    const int blk = blockIdx.x;

    if (tid < HDIM) hcode[tid] = tanhf(t[0] * hw1[tid] + hb1[tid]);
    __syncthreads();

    if (blk < 32) {
        const int d = blk;
        // 64 weight rows (d*64+p), half-row per thread: thread i does row
        // d*64+(i>>1), hw2 half (i&1): 8 float4. Combine halves via shfl_xor.
        {
            const int p    = tid >> 1;
            const int half = tid & 1;
            const int row  = d * PREV + p;
            const float4* r4 = reinterpret_cast<const float4*>(hw2 + (size_t)row * HDIM) + half * 8;
            const float*  hc = hcode + half * 32;
            float acc = 0.f;
            #pragma unroll
            for (int q = 0; q < 8; ++q) {
                float4 u = r4[q];
                int j = q * 4;
                acc += u.x * hc[j] + u.y * hc[j + 1]
                     + u.z * hc[j + 2] + u.w * hc[j + 3];
            }
            acc += __shfl_xor(acc, 1, 64);      // combine the two halves
            if (half == 0) w1d[p] = acc + hb2[row];
        }
        __syncthreads();

        // M[h][d] for all 128 h (one per thread) + w2T[h][d] copy
        {
            const int h = tid;
            const float4* bwr = reinterpret_cast<const float4*>(bw + h * PREV);
            float acc = 0.f;
            #pragma unroll
            for (int q = 0; q < 16; ++q) {
                float4 u = bwr[q];
                int p = q * 4;
                acc += u.x * w1d[p]     + u.y * w1d[p + 1]
                     + u.z * w1d[p + 2] + u.w * w1d[p + 3];
            }
            ws[h * D + d] = acc;                    // M (scattered scalar store, tiny)
            ws[8192 + h * D + d] = w2[d * HID + h]; // w2T (coalesced read)
        }
    } else {
        // blk == 32: b1 then sbias
        if (tid < PREV) {
            const int i = D * PREV + tid;           // rows 2048..2111
            const float4* row = reinterpret_cast<const float4*>(hw2 + (size_t)i * HDIM);
            float acc = hb2[i];
            #pragma unroll
            for (int q = 0; q < 16; ++q) {
                float4 u = row[q];
                int j = q * 4;
                acc += u.x * hcode[j] + u.y * hcode[j + 1]
                     + u.z * hcode[j + 2] + u.w * hcode[j + 3];
            }
            b1s[tid] = acc;
        }
        __syncthreads();
        {   // sbias[h], one h per thread
            const float4* bwr = reinterpret_cast<const float4*>(bw + tid * PREV);
            float acc = bb[tid];
            #pragma unroll
            for (int q = 0; q < 16; ++q) {
                float4 u = bwr[q];
                int p = q * 4;
                acc += u.x * b1s[p]     + u.y * b1s[p + 1]
                     + u.z * b1s[p + 2] + u.w * b1s[p + 3];
            }
            ws[4096 + tid] = acc;
        }
    }
}

// grid 256 x 512 threads -- UNCHANGED from verified R3 kernel.
__global__ __launch_bounds__(TPB) void main_kernel(
    const float* __restrict__ y,
    const float* __restrict__ ws,
    const float* __restrict__ b2,
    float* __restrict__ out)
{
    __shared__ float Ms[HID][36];
    __shared__ float Ws[HID][36];
    __shared__ float xs[BPB][36];
    __shared__ __align__(16) float os[BPB][33];
    __shared__ float sbias_s[HID];
    __shared__ float cs_s[HID];
    __shared__ float b2s[D];

    const int tid = threadIdx.x;
    const int blk = blockIdx.x;

    {
        const float4* m4 = reinterpret_cast<const float4*>(ws);
        const float4* w4 = reinterpret_cast<const float4*>(ws + 8192);
        #pragma unroll
        for (int it = 0; it < 2; ++it) {
            int i = it * TPB + tid;
            int h = i >> 3;
            int dq = (i & 7) << 2;
            *reinterpret_cast<float4*>(&Ms[h][dq]) = m4[i];
            *reinterpret_cast<float4*>(&Ws[h][dq]) = w4[i];
        }
    }
    {
        const float4* yb4 = reinterpret_cast<const float4*>(y + (size_t)blk * BPB * 33);
        if (tid < 264) {
            float4 v = yb4[tid];
            int base = 4 * tid;
            int r0 = base / 33, c0 = base - 33 * r0;
            float vv[4] = { v.x, v.y, v.z, v.w };
            #pragma unroll
            for (int j = 0; j < 4; ++j) {
                int c = c0 + j, r = r0;
                if (c >= 33) { c -= 33; r += 1; }
                xs[r][c] = vv[j];
            }
        }
    }
    if (tid >= 264 && tid < 264 + HID) sbias_s[tid - 264] = ws[4096 + (tid - 264)];
    if (tid >= 392 && tid < 392 + D)   b2s[tid - 392] = b2[tid - 392];
    __syncthreads();

    if (tid < HID) {
        const float4* mr = reinterpret_cast<const float4*>(&Ms[tid][0]);
        const float4* wr = reinterpret_cast<const float4*>(&Ws[tid][0]);
        float acc = 0.f;
        #pragma unroll
        for (int q = 0; q < 8; ++q) {
            float4 m = mr[q], w = wr[q];
            acc += m.x * w.x + m.y * w.y + m.z * w.z + m.w * w.w;
        }
        cs_s[tid] = acc;
    }

    const int hg   = tid & 31;
    const int pair = tid >> 5;
    const int b0 = 2 * pair, b1 = b0 + 1;

    float xr0[D], xr1[D];
    {
        const float4* x0 = reinterpret_cast<const float4*>(&xs[b0][0]);
        const float4* x1 = reinterpret_cast<const float4*>(&xs[b1][0]);
        #pragma unroll
        for (int q = 0; q < 8; ++q) {
            float4 v0 = x0[q], v1 = x1[q];
            xr0[4*q] = v0.x; xr0[4*q+1] = v0.y; xr0[4*q+2] = v0.z; xr0[4*q+3] = v0.w;
            xr1[4*q] = v1.x; xr1[4*q+1] = v1.y; xr1[4*q+2] = v1.z; xr1[4*q+3] = v1.w;
        }
    }
    __syncthreads();

    float dx0[D], dx1[D];
    #pragma unroll
    for (int d = 0; d < D; ++d) { dx0[d] = 0.f; dx1[d] = 0.f; }
    float div0 = 0.f, div1 = 0.f;

    #pragma unroll
    for (int k = 0; k < 4; ++k) {
        const int h = (k << 5) | hg;
        float s0 = sbias_s[h], s1 = s0;
        const float4* mrow = reinterpret_cast<const float4*>(&Ms[h][0]);
        #pragma unroll
        for (int q = 0; q < 8; ++q) {
            float4 m = mrow[q];
            s0 += xr0[4*q]*m.x + xr0[4*q+1]*m.y + xr0[4*q+2]*m.z + xr0[4*q+3]*m.w;
            s1 += xr1[4*q]*m.x + xr1[4*q+1]*m.y + xr1[4*q+2]*m.z + xr1[4*q+3]*m.w;
        }
        float e0 = __expf(2.f * s0), e1 = __expf(2.f * s1);
        float a0 = 1.f - 2.f / (e0 + 1.f);
        float a1 = 1.f - 2.f / (e1 + 1.f);
        float ch = cs_s[h];
        div0 += (1.f - a0 * a0) * ch;
        div1 += (1.f - a1 * a1) * ch;
        const float4* wrow = reinterpret_cast<const float4*>(&Ws[h][0]);
        #pragma unroll
        for (int q = 0; q < 8; ++q) {
            float4 w = wrow[q];
            dx0[4*q]   += a0 * w.x;  dx1[4*q]   += a1 * w.x;
            dx0[4*q+1] += a0 * w.y;  dx1[4*q+1] += a1 * w.y;
            dx0[4*q+2] += a0 * w.z;  dx1[4*q+2] += a1 * w.z;
            dx0[4*q+3] += a0 * w.w;  dx1[4*q+3] += a1 * w.w;
        }
    }

    #pragma unroll
    for (int d = 0; d < D; ++d) {
        dx0[d] = reduce32(dx0[d]);
        dx1[d] = reduce32(dx1[d]);
    }
    div0 = reduce32(div0);
    div1 = reduce32(div1);

    if (hg == 16) {
        #pragma unroll
        for (int d = 0; d < D; ++d) {
            os[b0][d] = dx0[d] + b2s[d];
            os[b1][d] = dx1[d] + b2s[d];
        }
        os[b0][D] = -div0;
        os[b1][D] = -div1;
    }
    __syncthreads();

    {
        const float4* os4 = reinterpret_cast<const float4*>(&os[0][0]);
        float4* ob4 = reinterpret_cast<float4*>(out + (size_t)blk * BPB * 33);
        if (tid < 264) ob4[tid] = os4[tid];
    }
}

extern "C" void kernel_launch(void* const* d_in, const int* in_sizes, int n_in,
                              void* d_out, int out_size, void* d_ws, size_t ws_size,
                              hipStream_t stream) {
    const float* y   = (const float*)d_in[0];
    const float* t   = (const float*)d_in[1];
    const float* hw1 = (const float*)d_in[2];
    const float* hb1 = (const float*)d_in[3];
    const float* hw2 = (const float*)d_in[4];
    const float* hb2 = (const float*)d_in[5];
    const float* bw  = (const float*)d_in[6];
    const float* bb  = (const float*)d_in[7];
    const float* w2  = (const float*)d_in[8];
    const float* b2  = (const float*)d_in[9];
    float* ws  = (float*)d_ws;
    float* out = (float*)d_out;

    hipLaunchKernelGGL(prep_kernel, dim3(33), dim3(128), 0, stream,
                       t, hw1, hb1, hw2, hb2, bw, bb, w2, ws);
    hipLaunchKernelGGL(main_kernel, dim3(8192 / BPB), dim3(TPB), 0, stream,
                       y, ws, b2, out);
}